// Round 7
// baseline (319.094 us; speedup 1.0000x reference)
//
#include <hip/hip_runtime.h>
#include <hip/hip_bf16.h>

// ---------------------------------------------------------------------------
// Transformer block (LN1 -> QKV -> MHA -> proj+res -> LN2 -> MLP+res)
// B=2, L=2048, D=768, H=12, hd=64, MLP=3072. fp32 in/out, bf16 MFMA inside.
// Round 7: proj/MLP2 back to 64^2 grid (3 blk/CU) with BK=64 (8 MFMA/step);
// attn K/V staging via global_load_lds (linear LDS), exp2-domain softmax,
// defer-max rescale skip (T13).
// ---------------------------------------------------------------------------

#define DIM     768
#define SEQ     2048
#define BATCH   2
#define NHEAD   12
#define HD      64
#define MLPH    3072
#define ROWS    (BATCH * SEQ)      // 4096
#define QKVW    (3 * DIM)          // 2304
#define SCALE_LOG2E 0.18033688011112042f   // 64^-0.5 * log2(e)

typedef __attribute__((ext_vector_type(8))) short          bf16x8;
typedef __attribute__((ext_vector_type(8))) unsigned short ushort8;
typedef __attribute__((ext_vector_type(4))) unsigned short ushort4v;
typedef __attribute__((ext_vector_type(2))) unsigned int   u32x2;
typedef __attribute__((ext_vector_type(4))) float          f32x4;

__device__ __forceinline__ float bf2f(unsigned short u) {
    union { unsigned int i; float f; } c; c.i = ((unsigned int)u) << 16; return c.f;
}
__device__ __forceinline__ unsigned short f2bf(float f) {
    union { float f; unsigned int i; } c; c.f = f;
    unsigned int i = c.i;
    return (unsigned short)((i + 0x7FFFu + ((i >> 16) & 1u)) >> 16);
}
__device__ __forceinline__ unsigned int cvt_pk_bf16(float lo, float hi) {
    unsigned int r;
    asm volatile("v_cvt_pk_bf16_f32 %0, %1, %2" : "=v"(r) : "v"(lo), "v"(hi));
    return r;
}
// XOR-swizzled LDS index for P (64-el rows, chunk-of-8 swizzle; b128-safe).
__device__ __forceinline__ int swz(int row, int el) {
    return (row << 6) + (el ^ ((row & 7) << 3));
}

// async global->LDS, 16B per lane: lane l writes LDS base + l*16 (linear);
// global source address is per-lane.
__device__ __forceinline__ void gll16(const unsigned short* g, unsigned short* l) {
    __builtin_amdgcn_global_load_lds(
        (const __attribute__((address_space(1))) unsigned int*)g,
        (__attribute__((address_space(3))) unsigned int*)l,
        16, 0, 0);
}

// --------------------- fused weight transpose+cast (one launch) ------------
__global__ __launch_bounds__(256) void transpose_cast_all(
    const float* __restrict__ w0, unsigned short* __restrict__ o0,
    const float* __restrict__ w1, unsigned short* __restrict__ o1,
    const float* __restrict__ w2, unsigned short* __restrict__ o2,
    const float* __restrict__ w3, unsigned short* __restrict__ o3)
{
    __shared__ float tile[32][33];
    const int bid = blockIdx.x;
    const float* in; unsigned short* out; int K, N, t;
    if (bid < 1728)      { in = w0; out = o0; K = 768;  N = 2304; t = bid; }
    else if (bid < 2304) { in = w1; out = o1; K = 768;  N = 768;  t = bid - 1728; }
    else if (bid < 4608) { in = w2; out = o2; K = 768;  N = 3072; t = bid - 2304; }
    else                 { in = w3; out = o3; K = 3072; N = 768;  t = bid - 4608; }
    const int nx = N / 32;
    const int n0 = (t % nx) * 32, k0 = (t / nx) * 32;
    const int tx = threadIdx.x, ty = threadIdx.y;   // block (32,8)
#pragma unroll
    for (int i = 0; i < 4; ++i)
        tile[ty + i * 8][tx] = in[(size_t)(k0 + ty + i * 8) * N + n0 + tx];
    __syncthreads();
#pragma unroll
    for (int i = 0; i < 4; ++i)
        out[(size_t)(n0 + ty + i * 8) * K + k0 + tx] = f2bf(tile[tx][ty + i * 8]);
}

// --------------------------------- layernorm -------------------------------
__global__ __launch_bounds__(256) void ln_fwd(
    const float* __restrict__ x, const float* __restrict__ w,
    unsigned short* __restrict__ out)
{
    const int row = blockIdx.x;
    const int tid = threadIdx.x;
    const size_t base = (size_t)row * DIM;
    float v0 = x[base + tid], v1 = x[base + tid + 256], v2 = x[base + tid + 512];
    float sum = v0 + v1 + v2;
    float sq  = v0 * v0 + v1 * v1 + v2 * v2;
#pragma unroll
    for (int off = 1; off < 64; off <<= 1) {
        sum += __shfl_xor(sum, off);
        sq  += __shfl_xor(sq,  off);
    }
    __shared__ float rs[4], rq[4];
    const int wid = tid >> 6, lane = tid & 63;
    if (lane == 0) { rs[wid] = sum; rq[wid] = sq; }
    __syncthreads();
    sum = rs[0] + rs[1] + rs[2] + rs[3];
    sq  = rq[0] + rq[1] + rq[2] + rq[3];
    const float mu   = sum * (1.0f / DIM);
    const float var  = sq * (1.0f / DIM) - mu * mu;
    const float rstd = rsqrtf(var + 1e-6f);
    out[base + tid]       = f2bf((v0 - mu) * rstd * w[tid]);
    out[base + tid + 256] = f2bf((v1 - mu) * rstd * w[tid + 256]);
    out[base + tid + 512] = f2bf((v2 - mu) * rstd * w[tid + 512]);
}

// ----------------------------------- GEMM ----------------------------------
// C[M][N] = A[M][K](bf16) x BT[N][K](bf16)^T.
// 3-stage LDS rotation, raw s_barrier + counted vmcnt(4) (never 0 mid-loop).
// Template BK; all configs have 4 gll/thread/stage.
// EPI 1: outf = res + C.  EPI 2: outb = bf16(gelu(C)).
// EPI 3 (QKV): q/k cols -> outb (qkv layout); v cols -> vt[b][h][d][L].
template<int EPI, int BM, int BN, int BK>
__global__ __launch_bounds__(256) void gemm_pipe(
    const unsigned short* __restrict__ A,
    const unsigned short* __restrict__ BT,
    const float* __restrict__ res,
    unsigned short* __restrict__ outb,
    float* __restrict__ outf,
    unsigned short* __restrict__ vt,
    int M, int N, int K)
{
    constexpr int WM = BM / 2, WN = BN / 2;
    constexpr int MI = WM / 16, NJ = WN / 16;
    constexpr int KK = BK / 32;                // k-chunks per step
    constexpr int RPG = 512 / BK;              // rows per gll16 (per wave)
    constexpr int CPR = BK / 8;                // 8-el chunks per row
    constexpr int NSA = BM * BK / 2048;        // A glls per thread per stage
    constexpr int NSB = BN * BK / 2048;
    static_assert(NSA + NSB == 4, "vmcnt constant assumes 4 gll/stage");
    __shared__ __align__(16) unsigned short As[3][BM * BK];
    __shared__ __align__(16) unsigned short Bs[3][BN * BK];
    const int tid = threadIdx.x, wid = tid >> 6;
    const int lane = tid & 63, l15 = lane & 15, g = lane >> 4;
    const int bm = blockIdx.x * BM, bn = blockIdx.y * BN;
    const int wm = (wid >> 1) * WM, wn = (wid & 1) * WN;

    const int lrow = lane / CPR, lcol = (lane % CPR) * 8;
    const unsigned short* ag = A  + (size_t)(bm + wid * RPG + lrow) * K + lcol;
    const unsigned short* bg = BT + (size_t)(bn + wid * RPG + lrow) * K + lcol;

    auto stage = [&](int buf, int k0) {
#pragma unroll
        for (int s = 0; s < NSA; ++s)
            gll16(ag + (size_t)(s * 4 * RPG) * K + k0,
                  &As[buf][(s * 4 * RPG + wid * RPG) * BK]);
#pragma unroll
        for (int s = 0; s < NSB; ++s)
            gll16(bg + (size_t)(s * 4 * RPG) * K + k0,
                  &Bs[buf][(s * 4 * RPG + wid * RPG) * BK]);
    };

    const int NS = K / BK;
    f32x4 acc[MI][NJ] = {};
    stage(0, 0);
    stage(1, BK);
    int cur = 0;
    for (int ks = 0; ks < NS; ++ks) {
        if (ks + 1 < NS) asm volatile("s_waitcnt vmcnt(4)" ::: "memory");
        else             asm volatile("s_waitcnt vmcnt(0)" ::: "memory");
        __builtin_amdgcn_s_barrier();
        __builtin_amdgcn_sched_barrier(0);
        if (ks + 2 < NS) {
            const int nb = (cur + 2 >= 3) ? cur - 1 : cur + 2;
            stage(nb, (ks + 2) * BK);
        }
        bf16x8 af[KK][MI], bfr[KK][NJ];
#pragma unroll
        for (int kk = 0; kk < KK; ++kk) {
#pragma unroll
            for (int i = 0; i < MI; ++i)
                af[kk][i] = *(const bf16x8*)&As[cur][(wm + i * 16 + l15) * BK + kk * 32 + g * 8];
#pragma unroll
            for (int j = 0; j < NJ; ++j)
                bfr[kk][j] = *(const bf16x8*)&Bs[cur][(wn + j * 16 + l15) * BK + kk * 32 + g * 8];
        }
#pragma unroll
        for (int kk = 0; kk < KK; ++kk)
#pragma unroll
            for (int i = 0; i < MI; ++i)
#pragma unroll
                for (int j = 0; j < NJ; ++j)
                    acc[i][j] = __builtin_amdgcn_mfma_f32_16x16x32_bf16(
                        af[kk][i], bfr[kk][j], acc[i][j], 0, 0, 0);
        cur = (cur + 1 >= 3) ? 0 : cur + 1;
    }
#pragma unroll
    for (int i = 0; i < MI; ++i)
#pragma unroll
        for (int j = 0; j < NJ; ++j) {
            const int row0 = bm + wm + i * 16 + g * 4;
            const int col  = bn + wn + j * 16 + l15;
            if (EPI == 3) {
                const int col0 = bn + wn + j * 16;     // wave-uniform
                const int rem0 = col0 % 192;
                if (rem0 < 128) {                      // q or k -> qkv layout
#pragma unroll
                    for (int r = 0; r < 4; ++r)
                        outb[(size_t)(row0 + r) * N + col] = f2bf(acc[i][j][r]);
                } else {                               // v -> vT[b][h][d][L]
                    const int hh = col0 / 192;
                    const int d  = rem0 - 128 + l15;
                    const int bb = row0 >> 11, ls = row0 & 2047;
                    ushort4v pv4;
#pragma unroll
                    for (int r = 0; r < 4; ++r) pv4[r] = f2bf(acc[i][j][r]);
                    *(ushort4v*)&vt[(((size_t)bb * NHEAD + hh) * HD + d) * SEQ + ls] = pv4;
                }
            } else {
#pragma unroll
                for (int r = 0; r < 4; ++r) {
                    const size_t idx = (size_t)(row0 + r) * N + col;
                    const float v = acc[i][j][r];
                    if (EPI == 1) {
                        outf[idx] = res[idx] + v;
                    } else if (EPI == 2) {
                        outb[idx] = f2bf(0.5f * v * (1.0f + erff(v * 0.70710678118654752f)));
                    } else {
                        outb[idx] = f2bf(v);
                    }
                }
            }
        }
}

// ------------------------------ MFMA flash attention -----------------------
// K from qkv (row-major), V from vT[b][h][d][L] (already transposed).
// Block = 256 thr (4 waves), one (b,h), 64 q rows (16/wave). KV tiles of 64.
// K/V staged via global_load_lds (linear LDS, dbuf; issue-early, compute
// covers latency, __syncthreads drains). exp2-domain softmax + defer-max.
__global__ __launch_bounds__(256) void attn_mfma(
    const unsigned short* __restrict__ qkv,
    const unsigned short* __restrict__ vT,
    unsigned short* __restrict__ o)
{
    __shared__ __align__(16) unsigned short Ks[2][64 * 64];  // [buf][kv][d]
    __shared__ __align__(16) unsigned short Vs[2][64 * 64];  // [buf][d][kv]
    __shared__ unsigned short Ps[4][16 * 64];                // per-wave swz[q][kv]
    const int tid = threadIdx.x, wid = tid >> 6, lane = tid & 63;
    const int l15 = lane & 15, g = lane >> 4;
    const int qt = blockIdx.x, bh = blockIdx.y;
    const int b = bh / NHEAD, h = bh % NHEAD;
    const size_t rowbase = (size_t)b * SEQ;

    // Q B-fragments straight from global: q = l15, d = g*8 + j (+32)
    const int qrow = qt * 64 + wid * 16 + l15;
    bf16x8 qf0, qf1;
    {
        const unsigned short* qp = qkv + (rowbase + qrow) * QKVW + h * 192 + g * 8;
        qf0 = *(const bf16x8*)qp;
        qf1 = *(const bf16x8*)(qp + 32);
    }

    // gll staging: per wave, 2 glls of 8 rows each for K and V.
    // lane -> row = base + (lane>>3), chunk = (lane&7)*8.
    const unsigned short* kg = qkv + (rowbase + wid * 16 + (lane >> 3)) * QKVW
                                   + h * 192 + 64 + (lane & 7) * 8;
    const unsigned short* vg = vT + ((size_t)bh * HD + wid * 16 + (lane >> 3)) * SEQ
                                  + (lane & 7) * 8;
    const size_t kstep = (size_t)QKVW;

    auto stage = [&](int buf, int kt) {
#pragma unroll
        for (int s = 0; s < 2; ++s) {
            gll16(kg + ((size_t)kt * 64 + s * 8) * kstep, &Ks[buf][(wid * 16 + s * 8) * 64]);
            gll16(vg + (size_t)kt * 64 + (size_t)(s * 8) * SEQ, &Vs[buf][(wid * 16 + s * 8) * 64]);
        }
    };

    float m_r = -1e30f, l_r = 0.f;
    f32x4 oacc[4] = {};                          // [dt]: d = dt*16+l15, q = g*4+r

    stage(0, 0);
    __syncthreads();
    int cur = 0;

    for (int kt = 0; kt < SEQ / 64; ++kt) {
        if (kt + 1 < SEQ / 64) stage(cur ^ 1, kt + 1);   // hidden under compute

        // S^T tiles: kv_local = st*16 + g*4 + r, q = l15 (exp2 domain)
        f32x4 sc4[4];
#pragma unroll
        for (int st = 0; st < 4; ++st) {
            bf16x8 k0 = *(const bf16x8*)&Ks[cur][(st * 16 + l15) * 64 + g * 8];
            bf16x8 k1 = *(const bf16x8*)&Ks[cur][(st * 16 + l15) * 64 + 32 + g * 8];
            f32x4 acc = {};
            acc = __builtin_amdgcn_mfma_f32_16x16x32_bf16(k0, qf0, acc, 0, 0, 0);
            acc = __builtin_amdgcn_mfma_f32_16x16x32_bf16(k1, qf1, acc, 0, 0, 0);
            sc4[st] = acc * SCALE_LOG2E;
        }

        // online softmax for q = l15 (stats replicated across the 4 g-groups)
        float tmax = -1e30f;
#pragma unroll
        for (int st = 0; st < 4; ++st)
#pragma unroll
            for (int r = 0; r < 4; ++r) tmax = fmaxf(tmax, sc4[st][r]);
        tmax = fmaxf(tmax, __shfl_xor(tmax, 16));
        tmax = fmaxf(tmax, __shfl_xor(tmax, 32));

        float mn = m_r;
        if (!__all(tmax - m_r <= 8.0f)) {        // rescale path (rare after warmup)
            mn = fmaxf(m_r, tmax);
            const float corr = exp2f(m_r - mn);
            m_r = mn;
            l_r *= corr;
#pragma unroll
            for (int r = 0; r < 4; ++r) {
                const float c = __shfl(corr, g * 4 + r);
#pragma unroll
                for (int dt = 0; dt < 4; ++dt) oacc[dt][r] *= c;
            }
        }

        float rsum = 0.f;
#pragma unroll
        for (int st = 0; st < 4; ++st) {
            const float p0 = exp2f(sc4[st][0] - mn);
            const float p1 = exp2f(sc4[st][1] - mn);
            const float p2 = exp2f(sc4[st][2] - mn);
            const float p3 = exp2f(sc4[st][3] - mn);
            rsum += (p0 + p1) + (p2 + p3);
            u32x2 w;
            w[0] = cvt_pk_bf16(p0, p1);
            w[1] = cvt_pk_bf16(p2, p3);
            *(u32x2*)&Ps[wid][swz(l15, st * 16 + g * 4)] = w;   // P[q][kv]
        }
        rsum += __shfl_xor(rsum, 16);
        rsum += __shfl_xor(rsum, 32);
        l_r += rsum;

        // PV: O[q][d] += P[q][kv] V[kv][d]; V^T rows read as b128
#pragma unroll
        for (int kk = 0; kk < 2; ++kk) {
            bf16x8 pfr = *(const bf16x8*)&Ps[wid][swz(l15, kk * 32 + g * 8)];
#pragma unroll
            for (int dt = 0; dt < 4; ++dt) {
                bf16x8 vf = *(const bf16x8*)&Vs[cur][(dt * 16 + l15) * 64 + kk * 32 + g * 8];
                oacc[dt] = __builtin_amdgcn_mfma_f32_16x16x32_bf16(pfr, vf, oacc[dt], 0, 0, 0);
            }
        }

        __syncthreads();     // drains this tile's glls; guards buf reuse
        cur ^= 1;
    }

#pragma unroll
    for (int r = 0; r < 4; ++r) {
        const float li  = __shfl(l_r, g * 4 + r);
        const float inv = 1.0f / li;
        const int   row = qt * 64 + wid * 16 + g * 4 + r;
#pragma unroll
        for (int dt = 0; dt < 4; ++dt)
            o[(rowbase + row) * DIM + h * HD + dt * 16 + l15] = f2bf(oacc[dt][r] * inv);
    }
}

// -------------------------------- launcher ---------------------------------
extern "C" void kernel_launch(void* const* d_in, const int* in_sizes, int n_in,
                              void* d_out, int out_size, void* d_ws, size_t ws_size,
                              hipStream_t stream)
{
    const float* x     = (const float*)d_in[0];
    const float* ln1w  = (const float*)d_in[2];
    const float* ln2w  = (const float*)d_in[3];
    const float* wqkv  = (const float*)d_in[4];
    const float* wproj = (const float*)d_in[5];
    const float* wmlp1 = (const float*)d_in[6];
    const float* wmlp2 = (const float*)d_in[7];
    float* out = (float*)d_out;

    char* ws = (char*)d_ws;
    size_t off = 0;
    auto alloc = [&](size_t nbytes) -> void* {
        void* p = (void*)(ws + off);
        off += (nbytes + 255) & ~(size_t)255;
        return p;
    };
    unsigned short* hb     = (unsigned short*)alloc((size_t)ROWS * DIM  * 2);
    unsigned short* qkvb   = (unsigned short*)alloc((size_t)ROWS * QKVW * 2);
    unsigned short* vt     = (unsigned short*)alloc((size_t)BATCH * NHEAD * HD * SEQ * 2);
    unsigned short* ob     = (unsigned short*)alloc((size_t)ROWS * DIM  * 2);
    float*          x1     = (float*)         alloc((size_t)ROWS * DIM  * 4);
    unsigned short* h2b    = (unsigned short*)alloc((size_t)ROWS * DIM  * 2);
    unsigned short* gb     = (unsigned short*)alloc((size_t)ROWS * MLPH * 2);
    unsigned short* wqkvT  = (unsigned short*)alloc((size_t)QKVW * DIM * 2);
    unsigned short* wprojT = (unsigned short*)alloc((size_t)DIM  * DIM * 2);
    unsigned short* wmlp1T = (unsigned short*)alloc((size_t)MLPH * DIM * 2);
    unsigned short* wmlp2T = (unsigned short*)alloc((size_t)DIM  * MLPH * 2);

    transpose_cast_all<<<6912, dim3(32, 8), 0, stream>>>(
        wqkv, wqkvT, wproj, wprojT, wmlp1, wmlp1T, wmlp2, wmlp2T);

    ln_fwd<<<ROWS, 256, 0, stream>>>(x, ln1w, hb);

    gemm_pipe<3, 128, 128, 32><<<dim3(ROWS / 128, QKVW / 128), 256, 0, stream>>>(
        hb, wqkvT, nullptr, qkvb, nullptr, vt, ROWS, QKVW, DIM);

    attn_mfma<<<dim3(SEQ / 64, BATCH * NHEAD), 256, 0, stream>>>(qkvb, vt, ob);

    gemm_pipe<1, 64, 64, 64><<<dim3(ROWS / 64, DIM / 64), 256, 0, stream>>>(
        ob, wprojT, x, nullptr, x1, nullptr, ROWS, DIM, DIM);

    ln_fwd<<<ROWS, 256, 0, stream>>>(x1, ln2w, h2b);

    gemm_pipe<2, 128, 128, 32><<<dim3(ROWS / 128, MLPH / 128), 256, 0, stream>>>(
        h2b, wmlp1T, nullptr, gb, nullptr, nullptr, ROWS, MLPH, DIM);

    gemm_pipe<1, 64, 64, 64><<<dim3(ROWS / 64, DIM / 64), 256, 0, stream>>>(
        gb, wmlp2T, x1, nullptr, out, nullptr, ROWS, DIM, MLPH);
}

// Round 8
// 297.741 us; speedup vs baseline: 1.0717x; 1.0717x over previous
//
#include <hip/hip_runtime.h>
#include <hip/hip_bf16.h>

// ---------------------------------------------------------------------------
// Transformer block (LN1 -> QKV -> MHA -> proj+res -> LN2 -> MLP+res)
// B=2, L=2048, D=768, H=12, hd=64, MLP=3072. fp32 in/out, bf16 MFMA inside.
// Round 8: QKV/MLP1 GEMMs -> 512-thread 8-wave blocks (24 waves/CU, m114
// overlap); attn reverted to round-6 structure (reg dbuf + full XOR swizzle)
// plus exp2-domain softmax and defer-max (T13).
// ---------------------------------------------------------------------------

#define DIM     768
#define SEQ     2048
#define BATCH   2
#define NHEAD   12
#define HD      64
#define MLPH    3072
#define ROWS    (BATCH * SEQ)      // 4096
#define QKVW    (3 * DIM)          // 2304
#define SCALE_LOG2E 0.18033688011112042f   // 64^-0.5 * log2(e)

typedef __attribute__((ext_vector_type(8))) short          bf16x8;
typedef __attribute__((ext_vector_type(8))) unsigned short ushort8;
typedef __attribute__((ext_vector_type(4))) unsigned short ushort4v;
typedef __attribute__((ext_vector_type(2))) unsigned int   u32x2;
typedef __attribute__((ext_vector_type(4))) float          f32x4;

__device__ __forceinline__ float bf2f(unsigned short u) {
    union { unsigned int i; float f; } c; c.i = ((unsigned int)u) << 16; return c.f;
}
__device__ __forceinline__ unsigned short f2bf(float f) {
    union { float f; unsigned int i; } c; c.f = f;
    unsigned int i = c.i;
    return (unsigned short)((i + 0x7FFFu + ((i >> 16) & 1u)) >> 16);
}
__device__ __forceinline__ unsigned int cvt_pk_bf16(float lo, float hi) {
    unsigned int r;
    asm volatile("v_cvt_pk_bf16_f32 %0, %1, %2" : "=v"(r) : "v"(lo), "v"(hi));
    return r;
}
// XOR-swizzled LDS index: 64-element rows, chunk-of-8 swizzle by row&7.
__device__ __forceinline__ int swz(int row, int el) {
    return (row << 6) + (el ^ ((row & 7) << 3));
}

// async global->LDS, 16B per lane: lane l writes LDS base + l*16 (linear).
__device__ __forceinline__ void gll16(const unsigned short* g, unsigned short* l) {
    __builtin_amdgcn_global_load_lds(
        (const __attribute__((address_space(1))) unsigned int*)g,
        (__attribute__((address_space(3))) unsigned int*)l,
        16, 0, 0);
}

// --------------------- fused weight transpose+cast (one launch) ------------
__global__ __launch_bounds__(256) void transpose_cast_all(
    const float* __restrict__ w0, unsigned short* __restrict__ o0,
    const float* __restrict__ w1, unsigned short* __restrict__ o1,
    const float* __restrict__ w2, unsigned short* __restrict__ o2,
    const float* __restrict__ w3, unsigned short* __restrict__ o3)
{
    __shared__ float tile[32][33];
    const int bid = blockIdx.x;
    const float* in; unsigned short* out; int K, N, t;
    if (bid < 1728)      { in = w0; out = o0; K = 768;  N = 2304; t = bid; }
    else if (bid < 2304) { in = w1; out = o1; K = 768;  N = 768;  t = bid - 1728; }
    else if (bid < 4608) { in = w2; out = o2; K = 768;  N = 3072; t = bid - 2304; }
    else                 { in = w3; out = o3; K = 3072; N = 768;  t = bid - 4608; }
    const int nx = N / 32;
    const int n0 = (t % nx) * 32, k0 = (t / nx) * 32;
    const int tx = threadIdx.x, ty = threadIdx.y;   // block (32,8)
#pragma unroll
    for (int i = 0; i < 4; ++i)
        tile[ty + i * 8][tx] = in[(size_t)(k0 + ty + i * 8) * N + n0 + tx];
    __syncthreads();
#pragma unroll
    for (int i = 0; i < 4; ++i)
        out[(size_t)(n0 + ty + i * 8) * K + k0 + tx] = f2bf(tile[tx][ty + i * 8]);
}

// --------------------------------- layernorm -------------------------------
__global__ __launch_bounds__(256) void ln_fwd(
    const float* __restrict__ x, const float* __restrict__ w,
    unsigned short* __restrict__ out)
{
    const int row = blockIdx.x;
    const int tid = threadIdx.x;
    const size_t base = (size_t)row * DIM;
    float v0 = x[base + tid], v1 = x[base + tid + 256], v2 = x[base + tid + 512];
    float sum = v0 + v1 + v2;
    float sq  = v0 * v0 + v1 * v1 + v2 * v2;
#pragma unroll
    for (int off = 1; off < 64; off <<= 1) {
        sum += __shfl_xor(sum, off);
        sq  += __shfl_xor(sq,  off);
    }
    __shared__ float rs[4], rq[4];
    const int wid = tid >> 6, lane = tid & 63;
    if (lane == 0) { rs[wid] = sum; rq[wid] = sq; }
    __syncthreads();
    sum = rs[0] + rs[1] + rs[2] + rs[3];
    sq  = rq[0] + rq[1] + rq[2] + rq[3];
    const float mu   = sum * (1.0f / DIM);
    const float var  = sq * (1.0f / DIM) - mu * mu;
    const float rstd = rsqrtf(var + 1e-6f);
    out[base + tid]       = f2bf((v0 - mu) * rstd * w[tid]);
    out[base + tid + 256] = f2bf((v1 - mu) * rstd * w[tid + 256]);
    out[base + tid + 512] = f2bf((v2 - mu) * rstd * w[tid + 512]);
}

// ------------------------- GEMM, 512-thread 8-wave -------------------------
// C[M][N] = A[M][K] x BT[N][K]^T. 128x128 tile, BK=32, wave tile 64x32 (2x4).
// 3-stage LDS rotation, s_barrier + counted vmcnt(2). 48KB LDS -> 3 blk/CU
// = 24 waves/CU. Each wave stages 16 rows of A and 16 of B (1 gll each).
// EPI 2: outb = bf16(gelu(C)).  EPI 3 (QKV): q/k -> outb; v -> vt[b][h][d][L].
template<int EPI>
__global__ __launch_bounds__(512) void gemm_pipe8(
    const unsigned short* __restrict__ A,
    const unsigned short* __restrict__ BT,
    unsigned short* __restrict__ outb,
    unsigned short* __restrict__ vt,
    int M, int N, int K)
{
    constexpr int MI = 4, NJ = 2;
    __shared__ __align__(16) unsigned short As[3][128 * 32];
    __shared__ __align__(16) unsigned short Bs[3][128 * 32];
    const int tid = threadIdx.x, wid = tid >> 6;
    const int lane = tid & 63, l15 = lane & 15, g = lane >> 4;
    const int bm = blockIdx.x * 128, bn = blockIdx.y * 128;
    const int wm = (wid >> 2) * 64, wn = (wid & 3) * 32;

    const unsigned short* ag = A  + (size_t)(bm + wid * 16 + (lane >> 2)) * K + (lane & 3) * 8;
    const unsigned short* bg = BT + (size_t)(bn + wid * 16 + (lane >> 2)) * K + (lane & 3) * 8;

    auto stage = [&](int buf, int k0) {
        gll16(ag + k0, &As[buf][wid * 16 * 32]);
        gll16(bg + k0, &Bs[buf][wid * 16 * 32]);
    };

    const int NS = K / 32;
    f32x4 acc[MI][NJ] = {};
    stage(0, 0);
    stage(1, 32);
    int cur = 0;
    for (int ks = 0; ks < NS; ++ks) {
        if (ks + 1 < NS) asm volatile("s_waitcnt vmcnt(2)" ::: "memory");
        else             asm volatile("s_waitcnt vmcnt(0)" ::: "memory");
        __builtin_amdgcn_s_barrier();
        __builtin_amdgcn_sched_barrier(0);
        if (ks + 2 < NS) {
            const int nb = (cur + 2 >= 3) ? cur - 1 : cur + 2;
            stage(nb, (ks + 2) * 32);
        }
        bf16x8 af[MI], bfr[NJ];
#pragma unroll
        for (int i = 0; i < MI; ++i)
            af[i] = *(const bf16x8*)&As[cur][(wm + i * 16 + l15) * 32 + g * 8];
#pragma unroll
        for (int j = 0; j < NJ; ++j)
            bfr[j] = *(const bf16x8*)&Bs[cur][(wn + j * 16 + l15) * 32 + g * 8];
#pragma unroll
        for (int i = 0; i < MI; ++i)
#pragma unroll
            for (int j = 0; j < NJ; ++j)
                acc[i][j] = __builtin_amdgcn_mfma_f32_16x16x32_bf16(
                    af[i], bfr[j], acc[i][j], 0, 0, 0);
        cur = (cur + 1 >= 3) ? 0 : cur + 1;
    }
#pragma unroll
    for (int i = 0; i < MI; ++i)
#pragma unroll
        for (int j = 0; j < NJ; ++j) {
            const int row0 = bm + wm + i * 16 + g * 4;
            const int col  = bn + wn + j * 16 + l15;
            if (EPI == 3) {
                const int col0 = bn + wn + j * 16;     // wave-uniform
                const int rem0 = col0 % 192;
                if (rem0 < 128) {                      // q or k -> qkv layout
#pragma unroll
                    for (int r = 0; r < 4; ++r)
                        outb[(size_t)(row0 + r) * N + col] = f2bf(acc[i][j][r]);
                } else {                               // v -> vT[b][h][d][L]
                    const int hh = col0 / 192;
                    const int d  = rem0 - 128 + l15;
                    const int bb = row0 >> 11, ls = row0 & 2047;
                    ushort4v pv4;
#pragma unroll
                    for (int r = 0; r < 4; ++r) pv4[r] = f2bf(acc[i][j][r]);
                    *(ushort4v*)&vt[(((size_t)bb * NHEAD + hh) * HD + d) * SEQ + ls] = pv4;
                }
            } else {
#pragma unroll
                for (int r = 0; r < 4; ++r) {
                    const size_t idx = (size_t)(row0 + r) * N + col;
                    const float v = acc[i][j][r];
                    outb[idx] = f2bf(0.5f * v * (1.0f + erff(v * 0.70710678118654752f)));
                }
            }
        }
}

// --------------------- GEMM, 256-thread (N=768 shapes) ---------------------
// 64x64 tile, BK=64, 3-stage, counted vmcnt(4). EPI 1: outf = res + C.
template<int EPI, int BM, int BN, int BK>
__global__ __launch_bounds__(256) void gemm_pipe(
    const unsigned short* __restrict__ A,
    const unsigned short* __restrict__ BT,
    const float* __restrict__ res,
    unsigned short* __restrict__ outb,
    float* __restrict__ outf,
    int M, int N, int K)
{
    constexpr int WM = BM / 2, WN = BN / 2;
    constexpr int MI = WM / 16, NJ = WN / 16;
    constexpr int KK = BK / 32;
    constexpr int RPG = 512 / BK;
    constexpr int CPR = BK / 8;
    constexpr int NSA = BM * BK / 2048;
    constexpr int NSB = BN * BK / 2048;
    static_assert(NSA + NSB == 4, "vmcnt constant assumes 4 gll/stage");
    __shared__ __align__(16) unsigned short As[3][BM * BK];
    __shared__ __align__(16) unsigned short Bs[3][BN * BK];
    const int tid = threadIdx.x, wid = tid >> 6;
    const int lane = tid & 63, l15 = lane & 15, g = lane >> 4;
    const int bm = blockIdx.x * BM, bn = blockIdx.y * BN;
    const int wm = (wid >> 1) * WM, wn = (wid & 1) * WN;

    const int lrow = lane / CPR, lcol = (lane % CPR) * 8;
    const unsigned short* ag = A  + (size_t)(bm + wid * RPG + lrow) * K + lcol;
    const unsigned short* bg = BT + (size_t)(bn + wid * RPG + lrow) * K + lcol;

    auto stage = [&](int buf, int k0) {
#pragma unroll
        for (int s = 0; s < NSA; ++s)
            gll16(ag + (size_t)(s * 4 * RPG) * K + k0,
                  &As[buf][(s * 4 * RPG + wid * RPG) * BK]);
#pragma unroll
        for (int s = 0; s < NSB; ++s)
            gll16(bg + (size_t)(s * 4 * RPG) * K + k0,
                  &Bs[buf][(s * 4 * RPG + wid * RPG) * BK]);
    };

    const int NS = K / BK;
    f32x4 acc[MI][NJ] = {};
    stage(0, 0);
    stage(1, BK);
    int cur = 0;
    for (int ks = 0; ks < NS; ++ks) {
        if (ks + 1 < NS) asm volatile("s_waitcnt vmcnt(4)" ::: "memory");
        else             asm volatile("s_waitcnt vmcnt(0)" ::: "memory");
        __builtin_amdgcn_s_barrier();
        __builtin_amdgcn_sched_barrier(0);
        if (ks + 2 < NS) {
            const int nb = (cur + 2 >= 3) ? cur - 1 : cur + 2;
            stage(nb, (ks + 2) * BK);
        }
        bf16x8 af[KK][MI], bfr[KK][NJ];
#pragma unroll
        for (int kk = 0; kk < KK; ++kk) {
#pragma unroll
            for (int i = 0; i < MI; ++i)
                af[kk][i] = *(const bf16x8*)&As[cur][(wm + i * 16 + l15) * BK + kk * 32 + g * 8];
#pragma unroll
            for (int j = 0; j < NJ; ++j)
                bfr[kk][j] = *(const bf16x8*)&Bs[cur][(wn + j * 16 + l15) * BK + kk * 32 + g * 8];
        }
#pragma unroll
        for (int kk = 0; kk < KK; ++kk)
#pragma unroll
            for (int i = 0; i < MI; ++i)
#pragma unroll
                for (int j = 0; j < NJ; ++j)
                    acc[i][j] = __builtin_amdgcn_mfma_f32_16x16x32_bf16(
                        af[kk][i], bfr[kk][j], acc[i][j], 0, 0, 0);
        cur = (cur + 1 >= 3) ? 0 : cur + 1;
    }
#pragma unroll
    for (int i = 0; i < MI; ++i)
#pragma unroll
        for (int j = 0; j < NJ; ++j)
#pragma unroll
            for (int r = 0; r < 4; ++r) {
                const int row = bm + wm + i * 16 + g * 4 + r;
                const int col = bn + wn + j * 16 + l15;
                const size_t idx = (size_t)row * N + col;
                const float v = acc[i][j][r];
                if (EPI == 1) outf[idx] = res[idx] + v;
                else          outb[idx] = f2bf(v);
            }
}

// ------------------------------ MFMA flash attention -----------------------
// Round-6 structure: reg-prefetch dbuf, ONE barrier/tile, XOR-swizzled
// Ks/Vs/Ps. Round-7 numerics: exp2-domain softmax + defer-max (THR=8).
__global__ __launch_bounds__(256) void attn_mfma(
    const unsigned short* __restrict__ qkv,
    const unsigned short* __restrict__ vT,
    unsigned short* __restrict__ o)
{
    __shared__ unsigned short Ks[2][64 * 64];    // [buf][swz(kv, d)]
    __shared__ unsigned short Vs[2][64 * 64];    // [buf][swz(d, kv)]
    __shared__ unsigned short Ps[4][16 * 64];    // per-wave [swz(q, kv)]
    const int tid = threadIdx.x, wid = tid >> 6, lane = tid & 63;
    const int l15 = lane & 15, g = lane >> 4;
    const int qt = blockIdx.x, bh = blockIdx.y;
    const int b = bh / NHEAD, h = bh % NHEAD;
    const size_t rowbase = (size_t)b * SEQ;

    // Q B-fragments straight from global: q = l15, d = g*8 + j (+32)
    const int qrow = qt * 64 + wid * 16 + l15;
    bf16x8 qf0, qf1;
    {
        const unsigned short* qp = qkv + (rowbase + qrow) * QKVW + h * 192 + g * 8;
        qf0 = *(const bf16x8*)qp;
        qf1 = *(const bf16x8*)(qp + 32);
    }

    // staging: thread covers rows srow, srow+32 (chunk sc..sc+7) of each tile
    const int srow = tid >> 3, sc = (tid & 7) * 8;
    const unsigned short* kg = qkv + (rowbase + srow) * QKVW + h * 192 + 64 + sc;
    const unsigned short* vg = vT + ((size_t)bh * HD + srow) * SEQ + sc;
    const size_t kstep = (size_t)64 * QKVW;

    float m_r = -1e30f, l_r = 0.f;
    f32x4 oacc[4] = {};                          // [dt]: d = dt*16+l15, q = g*4+r

    // prologue: stage tile 0 into buf 0
    ushort8 ka0 = *(const ushort8*)(kg);
    ushort8 ka1 = *(const ushort8*)(kg + 32 * QKVW);
    ushort8 va0 = *(const ushort8*)(vg);
    ushort8 va1 = *(const ushort8*)(vg + 32 * SEQ);
    *(ushort8*)&Ks[0][swz(srow, sc)]      = ka0;
    *(ushort8*)&Ks[0][swz(srow + 32, sc)] = ka1;
    *(ushort8*)&Vs[0][swz(srow, sc)]      = va0;
    *(ushort8*)&Vs[0][swz(srow + 32, sc)] = va1;
    __syncthreads();
    int cur = 0;

    for (int kt = 0; kt < SEQ / 64; ++kt) {
        const bool pf = (kt + 1 < SEQ / 64);
        if (pf) {                                // issue next tile's loads early
            const unsigned short* kp = kg + (size_t)(kt + 1) * kstep;
            const unsigned short* vp = vg + (kt + 1) * 64;
            ka0 = *(const ushort8*)(kp);
            ka1 = *(const ushort8*)(kp + 32 * QKVW);
            va0 = *(const ushort8*)(vp);
            va1 = *(const ushort8*)(vp + 32 * SEQ);
        }

        // S^T tiles: kv_local = st*16 + g*4 + r, q = l15 (exp2 domain)
        f32x4 sc4[4];
#pragma unroll
        for (int st = 0; st < 4; ++st) {
            bf16x8 k0 = *(const bf16x8*)&Ks[cur][swz(st * 16 + l15, g * 8)];
            bf16x8 k1 = *(const bf16x8*)&Ks[cur][swz(st * 16 + l15, 32 + g * 8)];
            f32x4 acc = {};
            acc = __builtin_amdgcn_mfma_f32_16x16x32_bf16(k0, qf0, acc, 0, 0, 0);
            acc = __builtin_amdgcn_mfma_f32_16x16x32_bf16(k1, qf1, acc, 0, 0, 0);
            sc4[st] = acc * SCALE_LOG2E;
        }

        // online softmax for q = l15 (stats replicated across the 4 g-groups)
        float tmax = -1e30f;
#pragma unroll
        for (int st = 0; st < 4; ++st)
#pragma unroll
            for (int r = 0; r < 4; ++r) tmax = fmaxf(tmax, sc4[st][r]);
        tmax = fmaxf(tmax, __shfl_xor(tmax, 16));
        tmax = fmaxf(tmax, __shfl_xor(tmax, 32));

        float mn = m_r;
        if (!__all(tmax - m_r <= 8.0f)) {        // defer-max: rescale rarely
            mn = fmaxf(m_r, tmax);
            const float corr = exp2f(m_r - mn);
            m_r = mn;
            l_r *= corr;
#pragma unroll
            for (int r = 0; r < 4; ++r) {
                const float c = __shfl(corr, g * 4 + r);
#pragma unroll
                for (int dt = 0; dt < 4; ++dt) oacc[dt][r] *= c;
            }
        }

        float rsum = 0.f;
#pragma unroll
        for (int st = 0; st < 4; ++st) {
            const float p0 = exp2f(sc4[st][0] - mn);
            const float p1 = exp2f(sc4[st][1] - mn);
            const float p2 = exp2f(sc4[st][2] - mn);
            const float p3 = exp2f(sc4[st][3] - mn);
            rsum += (p0 + p1) + (p2 + p3);
            u32x2 w;
            w[0] = cvt_pk_bf16(p0, p1);
            w[1] = cvt_pk_bf16(p2, p3);
            *(u32x2*)&Ps[wid][swz(l15, st * 16 + g * 4)] = w;   // P[q][kv]
        }
        rsum += __shfl_xor(rsum, 16);
        rsum += __shfl_xor(rsum, 32);
        l_r += rsum;

        // PV: O[q][d] += P[q][kv] V[kv][d]; V^T rows read as b128
#pragma unroll
        for (int kk = 0; kk < 2; ++kk) {
            bf16x8 pfr = *(const bf16x8*)&Ps[wid][swz(l15, kk * 32 + g * 8)];
#pragma unroll
            for (int dt = 0; dt < 4; ++dt) {
                bf16x8 vf = *(const bf16x8*)&Vs[cur][swz(dt * 16 + l15, kk * 32 + g * 8)];
                oacc[dt] = __builtin_amdgcn_mfma_f32_16x16x32_bf16(pfr, vf, oacc[dt], 0, 0, 0);
            }
        }

        if (pf) {                                // write next tile to other buf
            *(ushort8*)&Ks[cur ^ 1][swz(srow, sc)]      = ka0;
            *(ushort8*)&Ks[cur ^ 1][swz(srow + 32, sc)] = ka1;
            *(ushort8*)&Vs[cur ^ 1][swz(srow, sc)]      = va0;
            *(ushort8*)&Vs[cur ^ 1][swz(srow + 32, sc)] = va1;
        }
        __syncthreads();                         // one barrier per tile
        cur ^= 1;
    }

#pragma unroll
    for (int r = 0; r < 4; ++r) {
        const float li  = __shfl(l_r, g * 4 + r);
        const float inv = 1.0f / li;
        const int   row = qt * 64 + wid * 16 + g * 4 + r;
#pragma unroll
        for (int dt = 0; dt < 4; ++dt)
            o[(rowbase + row) * DIM + h * HD + dt * 16 + l15] = f2bf(oacc[dt][r] * inv);
    }
}

// -------------------------------- launcher ---------------------------------
extern "C" void kernel_launch(void* const* d_in, const int* in_sizes, int n_in,
                              void* d_out, int out_size, void* d_ws, size_t ws_size,
                              hipStream_t stream)
{
    const float* x     = (const float*)d_in[0];
    const float* ln1w  = (const float*)d_in[2];
    const float* ln2w  = (const float*)d_in[3];
    const float* wqkv  = (const float*)d_in[4];
    const float* wproj = (const float*)d_in[5];
    const float* wmlp1 = (const float*)d_in[6];
    const float* wmlp2 = (const float*)d_in[7];
    float* out = (float*)d_out;

    char* ws = (char*)d_ws;
    size_t off = 0;
    auto alloc = [&](size_t nbytes) -> void* {
        void* p = (void*)(ws + off);
        off += (nbytes + 255) & ~(size_t)255;
        return p;
    };
    unsigned short* hb     = (unsigned short*)alloc((size_t)ROWS * DIM  * 2);
    unsigned short* qkvb   = (unsigned short*)alloc((size_t)ROWS * QKVW * 2);
    unsigned short* vt     = (unsigned short*)alloc((size_t)BATCH * NHEAD * HD * SEQ * 2);
    unsigned short* ob     = (unsigned short*)alloc((size_t)ROWS * DIM  * 2);
    float*          x1     = (float*)         alloc((size_t)ROWS * DIM  * 4);
    unsigned short* h2b    = (unsigned short*)alloc((size_t)ROWS * DIM  * 2);
    unsigned short* gb     = (unsigned short*)alloc((size_t)ROWS * MLPH * 2);
    unsigned short* wqkvT  = (unsigned short*)alloc((size_t)QKVW * DIM * 2);
    unsigned short* wprojT = (unsigned short*)alloc((size_t)DIM  * DIM * 2);
    unsigned short* wmlp1T = (unsigned short*)alloc((size_t)MLPH * DIM * 2);
    unsigned short* wmlp2T = (unsigned short*)alloc((size_t)DIM  * MLPH * 2);

    transpose_cast_all<<<6912, dim3(32, 8), 0, stream>>>(
        wqkv, wqkvT, wproj, wprojT, wmlp1, wmlp1T, wmlp2, wmlp2T);

    ln_fwd<<<ROWS, 256, 0, stream>>>(x, ln1w, hb);

    gemm_pipe8<3><<<dim3(ROWS / 128, QKVW / 128), 512, 0, stream>>>(
        hb, wqkvT, qkvb, vt, ROWS, QKVW, DIM);

    attn_mfma<<<dim3(SEQ / 64, BATCH * NHEAD), 256, 0, stream>>>(qkvb, vt, ob);

    gemm_pipe<1, 64, 64, 64><<<dim3(ROWS / 64, DIM / 64), 256, 0, stream>>>(
        ob, wprojT, x, nullptr, x1, ROWS, DIM, DIM);

    ln_fwd<<<ROWS, 256, 0, stream>>>(x1, ln2w, h2b);

    gemm_pipe8<2><<<dim3(ROWS / 128, MLPH / 128), 512, 0, stream>>>(
        h2b, wmlp1T, gb, nullptr, ROWS, MLPH, DIM);

    gemm_pipe<1, 64, 64, 64><<<dim3(ROWS / 64, DIM / 64), 256, 0, stream>>>(
        gb, wmlp2T, x1, nullptr, out, ROWS, DIM, MLPH);
}